// Round 1
// 1476.806 us; speedup vs baseline: 1.3936x; 1.3936x over previous
//
#include <hip/hip_runtime.h>
#include <hip/hip_bf16.h>
#include <math.h>

#define B_ 128
#define T_ 32
#define IN_ 512
#define H_ 512
#define M_ 16
#define WC_ 20
#define R_ 4
#define RW_ 80
#define NNIN_ 592
#define IFACE_ 163
#define K1P_ 1120
#define K2P_ 1024
#define KOP_ 608
#define CLIP_ 20.0f
#define EPS_ 1e-6f
#define DELTA_ 5e-6f

typedef __bf16 bf16x8 __attribute__((ext_vector_type(8)));
typedef float f32x4 __attribute__((ext_vector_type(4)));

__device__ __forceinline__ float sigmoidf_(float x) { return 1.0f / (1.0f + expf(-x)); }
__device__ __forceinline__ float softplusf_(float x) {
    return fmaxf(x, 0.0f) + log1pf(expf(-fabsf(x)));
}
__device__ __forceinline__ void split2(float v, __bf16* hp, __bf16* lp) {
    __bf16 h = (__bf16)v;
    *hp = h;
    *lp = (__bf16)(v - (float)h);
}

// ---------------------------------------------------------------------------
// Parameter block for the slot kernel. Weights: single bf16 limb (hi only);
// activations remain split hi/lo.
// ---------------------------------------------------------------------------
struct P {
    const float *x, *bih0, *bhh0, *bih1, *bhh1, *Wif0, *Wif1, *bif0, *bif1, *bout;
    float* out;
    __bf16 *a10h[4], *a10l[4];   // [x | 0 | h00], stride K1P
    __bf16 *a11h[4], *a11l[4];   // [out0 | rv0 | h10], stride K1P
    __bf16 *a20h[4], *a20l[4];   // [h0A | h01], stride K2P
    __bf16 *a21h[4], *a21l[4];   // [h1A | h11], stride K2P
    __bf16 *yh[4],  *yl[4];      // [out1 | rv1 | pad], stride KOP
    float *c00, *c01, *c10, *c11;
    float *mem0, *link0, *prec0, *rw0, *ww0, *us0;
    float *mem1, *link1, *prec1, *rw1, *ww1, *us1;
    __bf16 *w10, *w20, *w11, *w21, *wo;
};

// ---------------------------------------------------------------------------
// Fused LSTM GEMM tile: 16x16 (batch x hidden) of all 4 gates, 4 waves split
// K, LDS reduce, wave0 runs LSTM pointwise epilogue. W single-limb:
// acc += ah*w + al*w (2 MFMAs).
// ---------------------------------------------------------------------------
__device__ __forceinline__ void gemm_lstm_tile(
    int tid, int jt, int mt, float* red,
    const __bf16* Ah, const __bf16* Al, int KS,
    const __bf16* W, int nsteps,
    const float* b1, const float* b2, float* cst,
    __bf16* d1h, __bf16* d1l, int st1, int off1,
    __bf16* d2h, __bf16* d2l, int st2, int off2, int clip2)
{
    const int wave = tid >> 6, lane = tid & 63;
    const int l15 = lane & 15, quad = lane >> 4;
    const int j0 = jt * 16, m0 = mt * 16;

    f32x4 acc[4];
    #pragma unroll
    for (int g = 0; g < 4; ++g)
        #pragma unroll
        for (int i = 0; i < 4; ++i) acc[g][i] = 0.f;

    const int ks = (wave * nsteps) >> 2;
    const int ke = ((wave + 1) * nsteps) >> 2;

    size_t aoff = (size_t)(m0 + l15) * KS + ks * 32 + quad * 8;
    size_t woff[4];
    #pragma unroll
    for (int g = 0; g < 4; ++g)
        woff[g] = (size_t)(g * 512 + j0 + l15) * KS + ks * 32 + quad * 8;

    for (int s = ks; s < ke; ++s) {
        bf16x8 ah = *(const bf16x8*)(Ah + aoff);
        bf16x8 al = *(const bf16x8*)(Al + aoff);
        aoff += 32;
        #pragma unroll
        for (int g = 0; g < 4; ++g) {
            bf16x8 wh = *(const bf16x8*)(W + woff[g]);
            woff[g] += 32;
            acc[g] = __builtin_amdgcn_mfma_f32_16x16x32_bf16(ah, wh, acc[g], 0, 0, 0);
            acc[g] = __builtin_amdgcn_mfma_f32_16x16x32_bf16(al, wh, acc[g], 0, 0, 0);
        }
    }

    if (wave > 0) {
        #pragma unroll
        for (int g = 0; g < 4; ++g)
            #pragma unroll
            for (int r = 0; r < 4; ++r)
                red[((g * 4 + r) * 3 + (wave - 1)) * 64 + lane] = acc[g][r];
    }
    __syncthreads();
    if (wave == 0) {
        const int col = j0 + l15;
        float bg[4];
        #pragma unroll
        for (int g = 0; g < 4; ++g) bg[g] = b1[g * 512 + col] + b2[g * 512 + col];
        #pragma unroll
        for (int r = 0; r < 4; ++r) {
            const int m = m0 + quad * 4 + r;
            float gv[4];
            #pragma unroll
            for (int g = 0; g < 4; ++g) {
                int i = g * 4 + r;
                gv[g] = acc[g][r] + red[(i * 3 + 0) * 64 + lane] + red[(i * 3 + 1) * 64 + lane]
                      + red[(i * 3 + 2) * 64 + lane] + bg[g];
            }
            float cold = cst[m * H_ + col];
            float cn = sigmoidf_(gv[1]) * cold + sigmoidf_(gv[0]) * tanhf(gv[2]);
            cst[m * H_ + col] = cn;
            float h = sigmoidf_(gv[3]) * tanhf(cn);
            split2(h, &d1h[(size_t)m * st1 + off1 + col], &d1l[(size_t)m * st1 + off1 + col]);
            float h2 = clip2 ? fminf(fmaxf(h, -CLIP_), CLIP_) : h;
            split2(h2, &d2h[(size_t)m * st2 + off2 + col], &d2l[(size_t)m * st2 + off2 + col]);
        }
    }
}

// ---------------------------------------------------------------------------
// Plain GEMM tile (out projection), W single-limb
// ---------------------------------------------------------------------------
__device__ __forceinline__ void gemm_plain_tile(
    int tid, int nt, int mt, float* red,
    const __bf16* Ah, const __bf16* Al, int AS,
    const __bf16* W, int WS,
    int nsteps, const float* bias, float* C, int ldc)
{
    const int wave = tid >> 6, lane = tid & 63;
    const int l15 = lane & 15, quad = lane >> 4;
    const int n0 = nt * 16, m0 = mt * 16;

    f32x4 acc;
    #pragma unroll
    for (int i = 0; i < 4; ++i) acc[i] = 0.f;

    const int ks = (wave * nsteps) >> 2;
    const int ke = ((wave + 1) * nsteps) >> 2;

    size_t aoff = (size_t)(m0 + l15) * AS + ks * 32 + quad * 8;
    size_t woff = (size_t)(n0 + l15) * WS + ks * 32 + quad * 8;

    for (int s = ks; s < ke; ++s) {
        bf16x8 ah = *(const bf16x8*)(Ah + aoff);
        bf16x8 al = *(const bf16x8*)(Al + aoff);
        bf16x8 wh = *(const bf16x8*)(W + woff);
        aoff += 32; woff += 32;
        acc = __builtin_amdgcn_mfma_f32_16x16x32_bf16(ah, wh, acc, 0, 0, 0);
        acc = __builtin_amdgcn_mfma_f32_16x16x32_bf16(al, wh, acc, 0, 0, 0);
    }

    if (wave > 0) {
        #pragma unroll
        for (int r = 0; r < 4; ++r) red[(r * 3 + (wave - 1)) * 64 + lane] = acc[r];
    }
    __syncthreads();
    if (wave == 0) {
        const int col = n0 + l15;
        const float bc = bias[col];
        #pragma unroll
        for (int r = 0; r < 4; ++r) {
            const int m = m0 + quad * 4 + r;
            float v = acc[r] + red[(r * 3 + 0) * 64 + lane] + red[(r * 3 + 1) * 64 + lane]
                    + red[(r * 3 + 2) * 64 + lane] + bc;
            C[(size_t)m * ldc + col] = v;
        }
    }
}

// ---------------------------------------------------------------------------
// DNC memory-step core (one block per batch element, 256 threads). S[0..162]
// holds the transformed iface vector on entry.
//
// All former single-thread LDS-walking sections (write softmax, argsort +
// cumprod allocation, read softmax) are replaced by 16-lane register code:
//  - softmax: width-16 __shfl_xor butterflies
//  - argsort+cumprod: rank-based (rank = #{j: u_j<u_m || (u_j==u_m && j<m)},
//    alloc_m = (1-u_m) * prod_{rank_j<rank_m} u_j) == stable argsort +
//    exclusive cumprod of the reference.
// ---------------------------------------------------------------------------
__device__ void mem_core(int b, int tid, float* S,
    float* mem, float* link, float* prec, float* rw,
    float* ww, float* usage, __bf16* rvh, __bf16* rvl, int rvst)
{
    float* sif     = S;
    float* modes   = S + 164;
    float* wwnewS  = S + 208;
    float* precold = S + 224;
    float* rwold   = S + 240;
    float* rwnewS  = S + 304;
    float* lnk     = S + 368;   // 256
    float* memS    = S + 624;   // 320

    // ---- phase A: load state, read-mode softmax (tiny, 4 threads) ----
    if (tid < M_)       precold[tid] = prec[(size_t)b * M_ + tid];
    if (tid < R_ * M_)  rwold[tid]   = rw[(size_t)b * R_ * M_ + tid];
    if (tid < M_ * M_)  lnk[tid]     = link[(size_t)b * M_ * M_ + tid];
    for (int i = tid; i < M_ * WC_; i += 256) memS[i] = mem[(size_t)b * M_ * WC_ + i];
    if (tid < R_) {
        float a0 = sif[151 + tid * 3], a1 = sif[152 + tid * 3], a2 = sif[153 + tid * 3];
        float mx = fmaxf(a0, fmaxf(a1, a2));
        float e0 = expf(a0 - mx), e1 = expf(a1 - mx), e2 = expf(a2 - mx);
        float s = e0 + e1 + e2;
        modes[tid * 3 + 0] = e0 / s; modes[tid * 3 + 1] = e1 / s; modes[tid * 3 + 2] = e2 / s;
    }
    __syncthreads();

    // ---- phase B: usage / write-weights / precedence, lanes 0..15 ----
    if (tid < M_) {
        const int m = tid;
        float wwold = ww[(size_t)b * M_ + m];
        float u = usage[(size_t)b * M_ + m];
        u = u + (1.f - u) * wwold;
        float psi = 1.f;
        #pragma unroll
        for (int r = 0; r < R_; ++r) psi *= (1.f - sif[145 + r] * rwold[r * 16 + m]);
        u *= psi;

        // write content weights (cosine vs pre-update memory) + softmax
        float kn2 = 0.f, mn2 = 0.f, dot = 0.f;
        #pragma unroll
        for (int w = 0; w < WC_; ++w) {
            float kv = sif[84 + w], mv = memS[m * WC_ + w];
            kn2 += kv * kv; mn2 += mv * mv; dot += kv * mv;
        }
        float c = dot / ((sqrtf(kn2) + EPS_) * (sqrtf(mn2) + EPS_)) * sif[104];
        float mx = c;
        #pragma unroll
        for (int off = 8; off; off >>= 1) mx = fmaxf(mx, __shfl_xor(mx, off, 16));
        float e = expf(c - mx);
        float se = e;
        #pragma unroll
        for (int off = 8; off; off >>= 1) se += __shfl_xor(se, off, 16);
        float wcw = e / se;

        // allocation weights via stable ranks (== argsort + excl. cumprod)
        float uu = DELTA_ + (1.f - DELTA_) * u;
        int rank = 0;
        #pragma unroll
        for (int j = 0; j < 16; ++j) {
            float uj = __shfl(uu, j, 16);
            if (uj < uu || (uj == uu && j < m)) ++rank;
        }
        float prod = 1.f;
        #pragma unroll
        for (int j = 0; j < 16; ++j) {
            float uj = __shfl(uu, j, 16);
            int   rj = __shfl(rank, j, 16);
            if (rj < rank) prod *= uj;
        }
        float alloc = (1.f - uu) * prod;

        float ag = sif[149], wg = sif[150];
        float wwn = wg * (ag * alloc + (1.f - ag) * wcw);
        float sw = wwn;
        #pragma unroll
        for (int off = 8; off; off >>= 1) sw += __shfl_xor(sw, off, 16);

        wwnewS[m] = wwn;
        usage[(size_t)b * M_ + m] = u;
        ww[(size_t)b * M_ + m]    = wwn;
        prec[(size_t)b * M_ + m]  = (1.f - sw) * precold[m] + wwn;
    }
    __syncthreads();

    // ---- phase C: memory + link update ----
    for (int i = tid; i < M_ * WC_; i += 256) {
        int m = i / WC_, w = i - m * WC_;
        float nm = memS[i] * (1.f - wwnewS[m] * sif[105 + w]) + wwnewS[m] * sif[125 + w];
        memS[i] = nm;
        mem[(size_t)b * M_ * WC_ + i] = nm;
    }
    if (tid < M_ * M_) {
        int i = tid >> 4, j = tid & 15;
        float v = (1.f - wwnewS[i] - wwnewS[j]) * lnk[tid] + wwnewS[i] * precold[j];
        if (i == j) v = 0.f;
        lnk[tid] = v;
        link[(size_t)b * M_ * M_ + tid] = v;
    }
    __syncthreads();

    // ---- phase D: read content weights + softmax + temporal mix, tid<64 ----
    if (tid < 64) {
        const int r = tid >> 4, m = tid & 15;
        float kn2 = 0.f, mn2 = 0.f, dot = 0.f;
        #pragma unroll
        for (int w = 0; w < WC_; ++w) {
            float kv = sif[r * WC_ + w], mv = memS[m * WC_ + w];
            kn2 += kv * kv; mn2 += mv * mv; dot += kv * mv;
        }
        float c = dot / ((sqrtf(kn2) + EPS_) * (sqrtf(mn2) + EPS_)) * sif[80 + r];
        float mx = c;
        #pragma unroll
        for (int off = 8; off; off >>= 1) mx = fmaxf(mx, __shfl_xor(mx, off, 16));
        float e = expf(c - mx);
        float se = e;
        #pragma unroll
        for (int off = 8; off; off >>= 1) se += __shfl_xor(se, off, 16);
        float rc = e / se;

        float fwd = 0.f, bwd = 0.f;
        #pragma unroll
        for (int j = 0; j < M_; ++j) fwd += lnk[m * 16 + j] * rwold[r * 16 + j];
        #pragma unroll
        for (int i2 = 0; i2 < M_; ++i2) bwd += rwold[r * 16 + i2] * lnk[i2 * 16 + m];
        float v = modes[r * 3 + 0] * bwd + modes[r * 3 + 1] * fwd + modes[r * 3 + 2] * rc;
        rwnewS[tid] = v;
        rw[(size_t)b * R_ * M_ + tid] = v;
    }
    __syncthreads();

    // ---- phase E: read vectors ----
    if (tid < RW_) {
        int r = tid / WC_, w = tid - r * WC_;
        float s = 0.f;
        #pragma unroll
        for (int m = 0; m < M_; ++m) s += rwnewS[r * 16 + m] * memS[m * WC_ + w];
        split2(s, &rvh[(size_t)b * rvst + IN_ + tid], &rvl[(size_t)b * rvst + IN_ + tid]);
    }
}

// ---------------------------------------------------------------------------
// iface GEMV (coalesced, 4 outputs per wave-iteration: 4 independent
// interleaved shfl-xor reduce chains; activations applied by lanes 0..3 in
// parallel) + mem step.
// ---------------------------------------------------------------------------
__device__ void mem_group(int b, int tid, float* smem,
    const __bf16* och, const __bf16* ocl, int ost,
    const float* Wif, const float* bif,
    float* mem, float* link, float* prec, float* rw, float* ww, float* usage,
    __bf16* rvh, __bf16* rvl)
{
    float* af = smem;        // 512
    float* S  = smem + 512;  // ~944
    for (int i = tid; i < 512; i += 256)
        af[i] = (float)och[(size_t)b * ost + i] + (float)ocl[(size_t)b * ost + i];
    __syncthreads();

    const int wave = tid >> 6, lane = tid & 63;
    float av[8];
    #pragma unroll
    for (int i = 0; i < 8; ++i) av[i] = af[lane * 8 + i];

    for (int base = wave * 4; base < IFACE_; base += 16) {
        const float* w0 = Wif + (size_t)base * 512 + lane * 8;
        const float* w1 = Wif + (size_t)min(base + 1, IFACE_ - 1) * 512 + lane * 8;
        const float* w2 = Wif + (size_t)min(base + 2, IFACE_ - 1) * 512 + lane * 8;
        const float* w3 = Wif + (size_t)min(base + 3, IFACE_ - 1) * 512 + lane * 8;
        float a0 = 0.f, a1 = 0.f, a2 = 0.f, a3 = 0.f;
        #pragma unroll
        for (int i = 0; i < 8; ++i) {
            a0 += av[i] * w0[i];
            a1 += av[i] * w1[i];
            a2 += av[i] * w2[i];
            a3 += av[i] * w3[i];
        }
        #pragma unroll
        for (int off = 32; off > 0; off >>= 1) {
            a0 += __shfl_xor(a0, off);
            a1 += __shfl_xor(a1, off);
            a2 += __shfl_xor(a2, off);
            a3 += __shfl_xor(a3, off);
        }
        if (lane < 4) {
            int o = base + lane;
            if (o < IFACE_) {
                float v = a0;
                if (lane == 1) v = a1;
                if (lane == 2) v = a2;
                if (lane == 3) v = a3;
                v += bif[o];
                float r;
                if (o < 80)        r = tanhf(v);
                else if (o < 84)   r = softplusf_(v);
                else if (o < 104)  r = tanhf(v);
                else if (o < 105)  r = softplusf_(v);
                else if (o < 145)  r = (o < 125) ? sigmoidf_(v) : tanhf(v);
                else if (o < 151)  r = sigmoidf_(v);
                else               r = v;
                S[o] = r;
            }
        }
    }
    __syncthreads();
    mem_core(b, tid, S, mem, link, prec, rw, ww, usage, rvh, rvl, ost);
}

// ---------------------------------------------------------------------------
// One pipeline slot: 7 independent stage instances + x-prefetch.
//   [0,256):      A0(t=s)
//   [256,512):    B0(t=s-1)
//   [512,640):    M0(t=s-2)
//   [640,896):    A1(t=s-3)
//   [896,1152):   B1(t=s-4)
//   [1152,1280):  M1(t=s-5)
//   [1280,1536):  Y(t=s-6)
//   [1536,1568):  x(s+1) convert
// ---------------------------------------------------------------------------
__global__ __launch_bounds__(256) void slot_kernel(P p, int s)
{
    __shared__ float smem[3072];
    const int blk = blockIdx.x, tid = threadIdx.x;

    if (blk < 256) {                       // A0(t=s)
        int t = s;
        if (t < T_) {
            gemm_lstm_tile(tid, blk & 31, blk >> 5, smem,
                p.a10h[t & 3], p.a10l[t & 3], K1P_, p.w10, K1P_ / 32,
                p.bih0, p.bhh0, p.c00,
                p.a10h[(t + 1) & 3], p.a10l[(t + 1) & 3], K1P_, NNIN_,
                p.a20h[t & 3], p.a20l[t & 3], K2P_, 0, 0);
        }
    } else if (blk < 512) {                // B0(t=s-1)
        int t = s - 1;
        if (t >= 0 && t < T_) {
            int b2 = blk - 256;
            gemm_lstm_tile(tid, b2 & 31, b2 >> 5, smem,
                p.a20h[t & 3], p.a20l[t & 3], K2P_, p.w20, K2P_ / 32,
                p.bih1, p.bhh1, p.c01,
                p.a20h[(t + 1) & 3], p.a20l[(t + 1) & 3], K2P_, H_,
                p.a11h[t & 3], p.a11l[t & 3], K1P_, 0, 1);
        }
    } else if (blk < 640) {                // M0(t=s-2)
        int t = s - 2;
        if (t >= 0 && t < T_) {
            mem_group(blk - 512, tid, smem,
                p.a11h[t & 3], p.a11l[t & 3], K1P_,
                p.Wif0, p.bif0,
                p.mem0, p.link0, p.prec0, p.rw0, p.ww0, p.us0,
                p.a11h[t & 3], p.a11l[t & 3]);
        }
    } else if (blk < 896) {                // A1(t=s-3)
        int t = s - 3;
        if (t >= 0 && t < T_) {
            int b2 = blk - 640;
            gemm_lstm_tile(tid, b2 & 31, b2 >> 5, smem,
                p.a11h[t & 3], p.a11l[t & 3], K1P_, p.w11, K1P_ / 32,
                p.bih0 + 2048, p.bhh0 + 2048, p.c10,
                p.a11h[(t + 1) & 3], p.a11l[(t + 1) & 3], K1P_, NNIN_,
                p.a21h[t & 3], p.a21l[t & 3], K2P_, 0, 0);
        }
    } else if (blk < 1152) {               // B1(t=s-4)
        int t = s - 4;
        if (t >= 0 && t < T_) {
            int b2 = blk - 896;
            gemm_lstm_tile(tid, b2 & 31, b2 >> 5, smem,
                p.a21h[t & 3], p.a21l[t & 3], K2P_, p.w21, K2P_ / 32,
                p.bih1 + 2048, p.bhh1 + 2048, p.c11,
                p.a21h[(t + 1) & 3], p.a21l[(t + 1) & 3], K2P_, H_,
                p.yh[t & 3], p.yl[t & 3], KOP_, 0, 1);
        }
    } else if (blk < 1280) {               // M1(t=s-5)
        int t = s - 5;
        if (t >= 0 && t < T_) {
            mem_group(blk - 1152, tid, smem,
                p.yh[t & 3], p.yl[t & 3], KOP_,
                p.Wif1, p.bif1,
                p.mem1, p.link1, p.prec1, p.rw1, p.ww1, p.us1,
                p.yh[t & 3], p.yl[t & 3]);
        }
    } else if (blk < 1536) {               // Y(t=s-6)
        int t = s - 6;
        if (t >= 0 && t < T_) {
            int tile = blk - 1280;
            gemm_plain_tile(tid, tile & 31, tile >> 5, smem,
                p.yh[t & 3], p.yl[t & 3], KOP_, p.wo, KOP_, KOP_ / 32,
                p.bout, p.out + (size_t)t * IN_, T_ * IN_);
        }
    } else {                               // x(s+1) convert
        int tn = s + 1;
        if (tn < T_) {
            for (int i = (blk - 1536) * 256 + tid; i < B_ * IN_; i += 32 * 256) {
                int b = i >> 9, j = i & 511;
                float v = p.x[((size_t)b * T_ + tn) * IN_ + j];
                split2(v, &p.a10h[tn & 3][(size_t)b * K1P_ + j],
                          &p.a10l[tn & 3][(size_t)b * K1P_ + j]);
            }
        }
    }
}

// ---------------------------------------------------------------------------
// Setup kernels
// ---------------------------------------------------------------------------
__global__ __launch_bounds__(256) void conv_hi(
    const float* __restrict__ s1, int K1, const float* __restrict__ s2, int K2,
    int Nsrc, __bf16* __restrict__ hi, int Kd)
{
    int k = blockIdx.x * 256 + threadIdx.x;
    int n = blockIdx.y;
    if (k >= Kd) return;
    float v = 0.f;
    if (n < Nsrc) {
        if (k < K1) v = s1[(size_t)n * K1 + k];
        else if (k < K1 + K2) v = s2[(size_t)n * K2 + (k - K1)];
    }
    hi[(size_t)n * Kd + k] = (__bf16)v;
}

__global__ __launch_bounds__(256) void build_inp(const float* __restrict__ x,
                                                 __bf16* __restrict__ a1h,
                                                 __bf16* __restrict__ a1l)
{
    int idx = blockIdx.x * 256 + threadIdx.x;
    if (idx >= B_ * IN_) return;
    int b = idx >> 9, j = idx & 511;
    float v = x[(size_t)b * T_ * IN_ + j];
    split2(v, &a1h[b * K1P_ + j], &a1l[b * K1P_ + j]);
}

// ---------------------------------------------------------------------------
extern "C" void kernel_launch(void* const* d_in, const int* in_sizes, int n_in,
                              void* d_out, int out_size, void* d_ws, size_t ws_size,
                              hipStream_t stream)
{
    const float* x       = (const float*)d_in[0];
    const float* W_ih0   = (const float*)d_in[1];
    const float* W_hh0   = (const float*)d_in[2];
    const float* b_ih0   = (const float*)d_in[3];
    const float* b_hh0   = (const float*)d_in[4];
    const float* W_ih1   = (const float*)d_in[5];
    const float* W_hh1   = (const float*)d_in[6];
    const float* b_ih1   = (const float*)d_in[7];
    const float* b_hh1   = (const float*)d_in[8];
    const float* W_iface = (const float*)d_in[9];
    const float* b_iface = (const float*)d_in[10];
    const float* W_out   = (const float*)d_in[11];
    const float* b_out   = (const float*)d_in[12];

    P p;
    p.x = x;
    p.bih0 = b_ih0; p.bhh0 = b_hh0; p.bih1 = b_ih1; p.bhh1 = b_hh1;
    p.Wif0 = W_iface; p.Wif1 = W_iface + (size_t)IFACE_ * H_;
    p.bif0 = b_iface; p.bif1 = b_iface + IFACE_;
    p.bout = b_out;
    p.out = (float*)d_out;

    char* ptr = (char*)d_ws;
    auto alloc = [&](size_t bytes) { char* r = ptr; ptr += (bytes + 255) & ~(size_t)255; return r; };

    // ---- zero zone (memset each call) ----
    char* zstart = ptr;
    for (int q = 0; q < 4; ++q) { p.a10h[q] = (__bf16*)alloc(B_ * K1P_ * 2); p.a10l[q] = (__bf16*)alloc(B_ * K1P_ * 2); }
    for (int q = 0; q < 4; ++q) { p.a11h[q] = (__bf16*)alloc(B_ * K1P_ * 2); p.a11l[q] = (__bf16*)alloc(B_ * K1P_ * 2); }
    for (int q = 0; q < 4; ++q) { p.a20h[q] = (__bf16*)alloc(B_ * K2P_ * 2); p.a20l[q] = (__bf16*)alloc(B_ * K2P_ * 2); }
    for (int q = 0; q < 4; ++q) { p.a21h[q] = (__bf16*)alloc(B_ * K2P_ * 2); p.a21l[q] = (__bf16*)alloc(B_ * K2P_ * 2); }
    for (int q = 0; q < 4; ++q) { p.yh[q]  = (__bf16*)alloc(B_ * KOP_ * 2);  p.yl[q]  = (__bf16*)alloc(B_ * KOP_ * 2); }
    p.c00 = (float*)alloc((size_t)B_ * H_ * 4);
    p.c01 = (float*)alloc((size_t)B_ * H_ * 4);
    p.c10 = (float*)alloc((size_t)B_ * H_ * 4);
    p.c11 = (float*)alloc((size_t)B_ * H_ * 4);
    p.mem0  = (float*)alloc((size_t)B_ * M_ * WC_ * 4);
    p.link0 = (float*)alloc((size_t)B_ * M_ * M_ * 4);
    p.prec0 = (float*)alloc((size_t)B_ * M_ * 4);
    p.rw0   = (float*)alloc((size_t)B_ * R_ * M_ * 4);
    p.ww0   = (float*)alloc((size_t)B_ * M_ * 4);
    p.us0   = (float*)alloc((size_t)B_ * M_ * 4);
    p.mem1  = (float*)alloc((size_t)B_ * M_ * WC_ * 4);
    p.link1 = (float*)alloc((size_t)B_ * M_ * M_ * 4);
    p.prec1 = (float*)alloc((size_t)B_ * M_ * 4);
    p.rw1   = (float*)alloc((size_t)B_ * R_ * M_ * 4);
    p.ww1   = (float*)alloc((size_t)B_ * M_ * 4);
    p.us1   = (float*)alloc((size_t)B_ * M_ * 4);
    size_t zbytes = (size_t)(ptr - zstart);

    // ---- weights, single bf16 limb (rewritten every call) ----
    p.w10 = (__bf16*)alloc(2048ull * K1P_ * 2);
    p.w11 = (__bf16*)alloc(2048ull * K1P_ * 2);
    p.w20 = (__bf16*)alloc(2048ull * K2P_ * 2);
    p.w21 = (__bf16*)alloc(2048ull * K2P_ * 2);
    p.wo  = (__bf16*)alloc(512ull * KOP_ * 2);

    hipMemsetAsync(zstart, 0, zbytes, stream);

    conv_hi<<<dim3((K1P_ + 255) / 256, 2048), 256, 0, stream>>>(
        W_ih0, NNIN_, W_hh0, H_, 2048, p.w10, K1P_);
    conv_hi<<<dim3((K1P_ + 255) / 256, 2048), 256, 0, stream>>>(
        W_ih0 + 2048ull * NNIN_, NNIN_, W_hh0 + 2048ull * H_, H_, 2048, p.w11, K1P_);
    conv_hi<<<dim3((K2P_ + 255) / 256, 2048), 256, 0, stream>>>(
        W_ih1, H_, W_hh1, H_, 2048, p.w20, K2P_);
    conv_hi<<<dim3((K2P_ + 255) / 256, 2048), 256, 0, stream>>>(
        W_ih1 + 2048ull * H_, W_hh1 ? H_ : H_, W_hh1 + 2048ull * H_, H_, 2048, p.w21, K2P_);
    conv_hi<<<dim3((KOP_ + 255) / 256, 512), 256, 0, stream>>>(
        W_out, NNIN_, nullptr, 0, 512, p.wo, KOP_);
    build_inp<<<(B_ * IN_ + 255) / 256, 256, 0, stream>>>(x, p.a10h[0], p.a10l[0]);

    // 38 pipeline slots cover t=0..31 for all 7 stages
    for (int s = 0; s < T_ + 6; ++s) {
        slot_kernel<<<1568, 256, 0, stream>>>(p, s);
    }
}

// Round 2
// 1027.844 us; speedup vs baseline: 2.0023x; 1.4368x over previous
//
#include <hip/hip_runtime.h>
#include <hip/hip_bf16.h>
#include <math.h>

#define B_ 128
#define T_ 32
#define IN_ 512
#define H_ 512
#define M_ 16
#define WC_ 20
#define R_ 4
#define RW_ 80
#define NNIN_ 592
#define IFACE_ 163
#define IFP_ 176
#define K1P_ 1120
#define K2P_ 1024
#define KOP_ 608
#define CLIP_ 20.0f
#define EPS_ 1e-6f
#define DELTA_ 5e-6f

typedef __bf16 bf16x8 __attribute__((ext_vector_type(8)));
typedef float f32x4 __attribute__((ext_vector_type(4)));

__device__ __forceinline__ float sigmoidf_(float x) { return 1.0f / (1.0f + expf(-x)); }
__device__ __forceinline__ float softplusf_(float x) {
    return fmaxf(x, 0.0f) + log1pf(expf(-fabsf(x)));
}
__device__ __forceinline__ void split2(float v, __bf16* hp, __bf16* lp) {
    __bf16 h = (__bf16)v;
    *hp = h;
    *lp = (__bf16)(v - (float)h);
}

// ---------------------------------------------------------------------------
// Parameter block. LSTM/out weights: single bf16 limb. iface weights: 2-limb
// bf16 (hi+lo). Activations split hi/lo.
// ---------------------------------------------------------------------------
struct P {
    const float *x, *bih0, *bhh0, *bih1, *bhh1, *bif0, *bif1, *bout;
    float* out;
    __bf16 *a10h[4], *a10l[4];   // [x | 0 | h00], stride K1P
    __bf16 *a11h[4], *a11l[4];   // [out0 | rv0 | h10], stride K1P
    __bf16 *a20h[4], *a20l[4];   // [h0A | h01], stride K2P
    __bf16 *a21h[4], *a21l[4];   // [h1A | h11], stride K2P
    __bf16 *yh[4],  *yl[4];      // [out1 | rv1 | pad], stride KOP
    float *c00, *c01, *c10, *c11;
    float *mem0, *link0, *prec0, *rw0, *ww0, *us0;
    float *mem1, *link1, *prec1, *rw1, *ww1, *us1;
    __bf16 *w10, *w20, *w11, *w21, *wo;
    __bf16 *wif0h, *wif0l, *wif1h, *wif1l;   // [IFP_ x 512]
    float *S0[2], *S1[2];                    // [B_ x IFP_] activated iface
};

// ---------------------------------------------------------------------------
// Fused LSTM GEMM tile: 16x16 (batch x hidden) of all 4 gates, 4 waves split
// K, LDS reduce, wave0 runs LSTM pointwise epilogue.
// ---------------------------------------------------------------------------
__device__ __forceinline__ void gemm_lstm_tile(
    int tid, int jt, int mt, float* red,
    const __bf16* Ah, const __bf16* Al, int KS,
    const __bf16* W, int nsteps,
    const float* b1, const float* b2, float* cst,
    __bf16* d1h, __bf16* d1l, int st1, int off1,
    __bf16* d2h, __bf16* d2l, int st2, int off2, int clip2)
{
    const int wave = tid >> 6, lane = tid & 63;
    const int l15 = lane & 15, quad = lane >> 4;
    const int j0 = jt * 16, m0 = mt * 16;

    f32x4 acc[4];
    #pragma unroll
    for (int g = 0; g < 4; ++g)
        #pragma unroll
        for (int i = 0; i < 4; ++i) acc[g][i] = 0.f;

    const int ks = (wave * nsteps) >> 2;
    const int ke = ((wave + 1) * nsteps) >> 2;

    size_t aoff = (size_t)(m0 + l15) * KS + ks * 32 + quad * 8;
    size_t woff[4];
    #pragma unroll
    for (int g = 0; g < 4; ++g)
        woff[g] = (size_t)(g * 512 + j0 + l15) * KS + ks * 32 + quad * 8;

    for (int s = ks; s < ke; ++s) {
        bf16x8 ah = *(const bf16x8*)(Ah + aoff);
        bf16x8 al = *(const bf16x8*)(Al + aoff);
        aoff += 32;
        #pragma unroll
        for (int g = 0; g < 4; ++g) {
            bf16x8 wh = *(const bf16x8*)(W + woff[g]);
            woff[g] += 32;
            acc[g] = __builtin_amdgcn_mfma_f32_16x16x32_bf16(ah, wh, acc[g], 0, 0, 0);
            acc[g] = __builtin_amdgcn_mfma_f32_16x16x32_bf16(al, wh, acc[g], 0, 0, 0);
        }
    }

    if (wave > 0) {
        #pragma unroll
        for (int g = 0; g < 4; ++g)
            #pragma unroll
            for (int r = 0; r < 4; ++r)
                red[((g * 4 + r) * 3 + (wave - 1)) * 64 + lane] = acc[g][r];
    }
    __syncthreads();
    if (wave == 0) {
        const int col = j0 + l15;
        float bg[4];
        #pragma unroll
        for (int g = 0; g < 4; ++g) bg[g] = b1[g * 512 + col] + b2[g * 512 + col];
        #pragma unroll
        for (int r = 0; r < 4; ++r) {
            const int m = m0 + quad * 4 + r;
            float gv[4];
            #pragma unroll
            for (int g = 0; g < 4; ++g) {
                int i = g * 4 + r;
                gv[g] = acc[g][r] + red[(i * 3 + 0) * 64 + lane] + red[(i * 3 + 1) * 64 + lane]
                      + red[(i * 3 + 2) * 64 + lane] + bg[g];
            }
            float cold = cst[m * H_ + col];
            float cn = sigmoidf_(gv[1]) * cold + sigmoidf_(gv[0]) * tanhf(gv[2]);
            cst[m * H_ + col] = cn;
            float h = sigmoidf_(gv[3]) * tanhf(cn);
            split2(h, &d1h[(size_t)m * st1 + off1 + col], &d1l[(size_t)m * st1 + off1 + col]);
            float h2 = clip2 ? fminf(fmaxf(h, -CLIP_), CLIP_) : h;
            split2(h2, &d2h[(size_t)m * st2 + off2 + col], &d2l[(size_t)m * st2 + off2 + col]);
        }
    }
}

// ---------------------------------------------------------------------------
// Plain GEMM tile (out projection), W single-limb
// ---------------------------------------------------------------------------
__device__ __forceinline__ void gemm_plain_tile(
    int tid, int nt, int mt, float* red,
    const __bf16* Ah, const __bf16* Al, int AS,
    const __bf16* W, int WS,
    int nsteps, const float* bias, float* C, int ldc)
{
    const int wave = tid >> 6, lane = tid & 63;
    const int l15 = lane & 15, quad = lane >> 4;
    const int n0 = nt * 16, m0 = mt * 16;

    f32x4 acc;
    #pragma unroll
    for (int i = 0; i < 4; ++i) acc[i] = 0.f;

    const int ks = (wave * nsteps) >> 2;
    const int ke = ((wave + 1) * nsteps) >> 2;

    size_t aoff = (size_t)(m0 + l15) * AS + ks * 32 + quad * 8;
    size_t woff = (size_t)(n0 + l15) * WS + ks * 32 + quad * 8;

    for (int s = ks; s < ke; ++s) {
        bf16x8 ah = *(const bf16x8*)(Ah + aoff);
        bf16x8 al = *(const bf16x8*)(Al + aoff);
        bf16x8 wh = *(const bf16x8*)(W + woff);
        aoff += 32; woff += 32;
        acc = __builtin_amdgcn_mfma_f32_16x16x32_bf16(ah, wh, acc, 0, 0, 0);
        acc = __builtin_amdgcn_mfma_f32_16x16x32_bf16(al, wh, acc, 0, 0, 0);
    }

    if (wave > 0) {
        #pragma unroll
        for (int r = 0; r < 4; ++r) red[(r * 3 + (wave - 1)) * 64 + lane] = acc[r];
    }
    __syncthreads();
    if (wave == 0) {
        const int col = n0 + l15;
        const float bc = bias[col];
        #pragma unroll
        for (int r = 0; r < 4; ++r) {
            const int m = m0 + quad * 4 + r;
            float v = acc[r] + red[(r * 3 + 0) * 64 + lane] + red[(r * 3 + 1) * 64 + lane]
                    + red[(r * 3 + 2) * 64 + lane] + bc;
            C[(size_t)m * ldc + col] = v;
        }
    }
}

// ---------------------------------------------------------------------------
// iface GEMM tile: S = act(out @ Wif^T + bif) for 16 batch rows x 16 iface
// cols. A 2-limb x W 2-limb, 3 MFMAs/step (al*wl dropped, ~2^-16 rel).
// K = 512 fixed -> 16 steps, 4 per wave.
// ---------------------------------------------------------------------------
__device__ __forceinline__ void gemm_iface_tile(
    int tid, int jt, int mt, float* red,
    const __bf16* Ah, const __bf16* Al, int AS,
    const __bf16* Wh, const __bf16* Wl,
    const float* bif, float* Sout)
{
    const int wave = tid >> 6, lane = tid & 63;
    const int l15 = lane & 15, quad = lane >> 4;
    const int n0 = jt * 16, m0 = mt * 16;

    f32x4 acc;
    #pragma unroll
    for (int i = 0; i < 4; ++i) acc[i] = 0.f;

    size_t aoff = (size_t)(m0 + l15) * AS + wave * 128 + quad * 8;
    size_t woff = (size_t)(n0 + l15) * 512 + wave * 128 + quad * 8;

    #pragma unroll
    for (int s = 0; s < 4; ++s) {
        bf16x8 ah = *(const bf16x8*)(Ah + aoff);
        bf16x8 al = *(const bf16x8*)(Al + aoff);
        bf16x8 wh = *(const bf16x8*)(Wh + woff);
        bf16x8 wl = *(const bf16x8*)(Wl + woff);
        aoff += 32; woff += 32;
        acc = __builtin_amdgcn_mfma_f32_16x16x32_bf16(ah, wh, acc, 0, 0, 0);
        acc = __builtin_amdgcn_mfma_f32_16x16x32_bf16(al, wh, acc, 0, 0, 0);
        acc = __builtin_amdgcn_mfma_f32_16x16x32_bf16(ah, wl, acc, 0, 0, 0);
    }

    if (wave > 0) {
        #pragma unroll
        for (int r = 0; r < 4; ++r) red[(r * 3 + (wave - 1)) * 64 + lane] = acc[r];
    }
    __syncthreads();
    if (wave == 0) {
        const int o = n0 + l15;
        const float bc = (o < IFACE_) ? bif[o] : 0.f;
        #pragma unroll
        for (int r = 0; r < 4; ++r) {
            const int m = m0 + quad * 4 + r;
            float v = acc[r] + red[(r * 3 + 0) * 64 + lane] + red[(r * 3 + 1) * 64 + lane]
                    + red[(r * 3 + 2) * 64 + lane] + bc;
            if (o < IFACE_) {
                float rr;
                if (o < 80)        rr = tanhf(v);
                else if (o < 84)   rr = softplusf_(v);
                else if (o < 104)  rr = tanhf(v);
                else if (o < 105)  rr = softplusf_(v);
                else if (o < 125)  rr = sigmoidf_(v);
                else if (o < 145)  rr = tanhf(v);
                else if (o < 151)  rr = sigmoidf_(v);
                else               rr = v;
                Sout[(size_t)m * IFP_ + o] = rr;
            }
        }
    }
}

// ---------------------------------------------------------------------------
// DNC memory-step core (one block per batch element, 256 threads). S[0..162]
// holds the transformed iface vector on entry. All reductions are 16-lane
// register code (shfl_xor softmax; rank-based alloc == stable argsort +
// exclusive cumprod).
// ---------------------------------------------------------------------------
__device__ void mem_core(int b, int tid, float* S,
    float* mem, float* link, float* prec, float* rw,
    float* ww, float* usage, __bf16* rvh, __bf16* rvl, int rvst)
{
    float* sif     = S;
    float* modes   = S + 164;
    float* wwnewS  = S + 208;
    float* precold = S + 224;
    float* rwold   = S + 240;
    float* rwnewS  = S + 304;
    float* lnk     = S + 368;   // 256
    float* memS    = S + 624;   // 320

    // ---- phase A: load state, read-mode softmax ----
    if (tid < M_)       precold[tid] = prec[(size_t)b * M_ + tid];
    if (tid < R_ * M_)  rwold[tid]   = rw[(size_t)b * R_ * M_ + tid];
    if (tid < M_ * M_)  lnk[tid]     = link[(size_t)b * M_ * M_ + tid];
    for (int i = tid; i < M_ * WC_; i += 256) memS[i] = mem[(size_t)b * M_ * WC_ + i];
    if (tid < R_) {
        float a0 = sif[151 + tid * 3], a1 = sif[152 + tid * 3], a2 = sif[153 + tid * 3];
        float mx = fmaxf(a0, fmaxf(a1, a2));
        float e0 = expf(a0 - mx), e1 = expf(a1 - mx), e2 = expf(a2 - mx);
        float s = e0 + e1 + e2;
        modes[tid * 3 + 0] = e0 / s; modes[tid * 3 + 1] = e1 / s; modes[tid * 3 + 2] = e2 / s;
    }
    __syncthreads();

    // ---- phase B: usage / write-weights / precedence, lanes 0..15 ----
    if (tid < M_) {
        const int m = tid;
        float wwold = ww[(size_t)b * M_ + m];
        float u = usage[(size_t)b * M_ + m];
        u = u + (1.f - u) * wwold;
        float psi = 1.f;
        #pragma unroll
        for (int r = 0; r < R_; ++r) psi *= (1.f - sif[145 + r] * rwold[r * 16 + m]);
        u *= psi;

        float kn2 = 0.f, mn2 = 0.f, dot = 0.f;
        #pragma unroll
        for (int w = 0; w < WC_; ++w) {
            float kv = sif[84 + w], mv = memS[m * WC_ + w];
            kn2 += kv * kv; mn2 += mv * mv; dot += kv * mv;
        }
        float c = dot / ((sqrtf(kn2) + EPS_) * (sqrtf(mn2) + EPS_)) * sif[104];
        float mx = c;
        #pragma unroll
        for (int off = 8; off; off >>= 1) mx = fmaxf(mx, __shfl_xor(mx, off, 16));
        float e = expf(c - mx);
        float se = e;
        #pragma unroll
        for (int off = 8; off; off >>= 1) se += __shfl_xor(se, off, 16);
        float wcw = e / se;

        float uu = DELTA_ + (1.f - DELTA_) * u;
        int rank = 0;
        #pragma unroll
        for (int j = 0; j < 16; ++j) {
            float uj = __shfl(uu, j, 16);
            if (uj < uu || (uj == uu && j < m)) ++rank;
        }
        float prod = 1.f;
        #pragma unroll
        for (int j = 0; j < 16; ++j) {
            float uj = __shfl(uu, j, 16);
            int   rj = __shfl(rank, j, 16);
            if (rj < rank) prod *= uj;
        }
        float alloc = (1.f - uu) * prod;

        float ag = sif[149], wg = sif[150];
        float wwn = wg * (ag * alloc + (1.f - ag) * wcw);
        float sw = wwn;
        #pragma unroll
        for (int off = 8; off; off >>= 1) sw += __shfl_xor(sw, off, 16);

        wwnewS[m] = wwn;
        usage[(size_t)b * M_ + m] = u;
        ww[(size_t)b * M_ + m]    = wwn;
        prec[(size_t)b * M_ + m]  = (1.f - sw) * precold[m] + wwn;
    }
    __syncthreads();

    // ---- phase C: memory + link update ----
    for (int i = tid; i < M_ * WC_; i += 256) {
        int m = i / WC_, w = i - m * WC_;
        float nm = memS[i] * (1.f - wwnewS[m] * sif[105 + w]) + wwnewS[m] * sif[125 + w];
        memS[i] = nm;
        mem[(size_t)b * M_ * WC_ + i] = nm;
    }
    if (tid < M_ * M_) {
        int i = tid >> 4, j = tid & 15;
        float v = (1.f - wwnewS[i] - wwnewS[j]) * lnk[tid] + wwnewS[i] * precold[j];
        if (i == j) v = 0.f;
        lnk[tid] = v;
        link[(size_t)b * M_ * M_ + tid] = v;
    }
    __syncthreads();

    // ---- phase D: read content weights + softmax + temporal mix, tid<64 ----
    if (tid < 64) {
        const int r = tid >> 4, m = tid & 15;
        float kn2 = 0.f, mn2 = 0.f, dot = 0.f;
        #pragma unroll
        for (int w = 0; w < WC_; ++w) {
            float kv = sif[r * WC_ + w], mv = memS[m * WC_ + w];
            kn2 += kv * kv; mn2 += mv * mv; dot += kv * mv;
        }
        float c = dot / ((sqrtf(kn2) + EPS_) * (sqrtf(mn2) + EPS_)) * sif[80 + r];
        float mx = c;
        #pragma unroll
        for (int off = 8; off; off >>= 1) mx = fmaxf(mx, __shfl_xor(mx, off, 16));
        float e = expf(c - mx);
        float se = e;
        #pragma unroll
        for (int off = 8; off; off >>= 1) se += __shfl_xor(se, off, 16);
        float rc = e / se;

        float fwd = 0.f, bwd = 0.f;
        #pragma unroll
        for (int j = 0; j < M_; ++j) fwd += lnk[m * 16 + j] * rwold[r * 16 + j];
        #pragma unroll
        for (int i2 = 0; i2 < M_; ++i2) bwd += rwold[r * 16 + i2] * lnk[i2 * 16 + m];
        float v = modes[r * 3 + 0] * bwd + modes[r * 3 + 1] * fwd + modes[r * 3 + 2] * rc;
        rwnewS[tid] = v;
        rw[(size_t)b * R_ * M_ + tid] = v;
    }
    __syncthreads();

    // ---- phase E: read vectors ----
    if (tid < RW_) {
        int r = tid / WC_, w = tid - r * WC_;
        float s = 0.f;
        #pragma unroll
        for (int m = 0; m < M_; ++m) s += rwnewS[r * 16 + m] * memS[m * WC_ + w];
        split2(s, &rvh[(size_t)b * rvst + IN_ + tid], &rvl[(size_t)b * rvst + IN_ + tid]);
    }
}

// ---------------------------------------------------------------------------
// mem stage: load precomputed activated iface row (from IF stage) + mem core.
// ---------------------------------------------------------------------------
__device__ void mem_group(int b, int tid, float* smem, const float* Sbuf,
    float* mem, float* link, float* prec, float* rw, float* ww, float* usage,
    __bf16* rvh, __bf16* rvl, int rvst)
{
    float* S = smem;
    for (int i = tid; i < IFACE_; i += 256) S[i] = Sbuf[(size_t)b * IFP_ + i];
    __syncthreads();
    mem_core(b, tid, S, mem, link, prec, rw, ww, usage, rvh, rvl, rvst);
}

// ---------------------------------------------------------------------------
// One pipeline slot: 9 stages + x-prefetch (1744 blocks).
//   [0,256):      A0(t=s)
//   [256,512):    B0(t=s-1)
//   [512,768):    A1(t=s-4)
//   [768,1024):   B1(t=s-5)
//   [1024,1152):  M0(t=s-3)
//   [1152,1280):  M1(t=s-7)
//   [1280,1536):  Y(t=s-8)
//   [1536,1624):  IF0(t=s-2)
//   [1624,1712):  IF1(t=s-6)
//   [1712,1744):  x(s+1) convert
// ---------------------------------------------------------------------------
__global__ __launch_bounds__(256) void slot_kernel(P p, int s)
{
    __shared__ float smem[3072];
    const int blk = blockIdx.x, tid = threadIdx.x;

    if (blk < 256) {                       // A0(t=s)
        int t = s;
        if (t < T_) {
            gemm_lstm_tile(tid, blk & 31, blk >> 5, smem,
                p.a10h[t & 3], p.a10l[t & 3], K1P_, p.w10, K1P_ / 32,
                p.bih0, p.bhh0, p.c00,
                p.a10h[(t + 1) & 3], p.a10l[(t + 1) & 3], K1P_, NNIN_,
                p.a20h[t & 3], p.a20l[t & 3], K2P_, 0, 0);
        }
    } else if (blk < 512) {                // B0(t=s-1)
        int t = s - 1;
        if (t >= 0 && t < T_) {
            int b2 = blk - 256;
            gemm_lstm_tile(tid, b2 & 31, b2 >> 5, smem,
                p.a20h[t & 3], p.a20l[t & 3], K2P_, p.w20, K2P_ / 32,
                p.bih1, p.bhh1, p.c01,
                p.a20h[(t + 1) & 3], p.a20l[(t + 1) & 3], K2P_, H_,
                p.a11h[t & 3], p.a11l[t & 3], K1P_, 0, 1);
        }
    } else if (blk < 768) {                // A1(t=s-4)
        int t = s - 4;
        if (t >= 0 && t < T_) {
            int b2 = blk - 512;
            gemm_lstm_tile(tid, b2 & 31, b2 >> 5, smem,
                p.a11h[t & 3], p.a11l[t & 3], K1P_, p.w11, K1P_ / 32,
                p.bih0 + 2048, p.bhh0 + 2048, p.c10,
                p.a11h[(t + 1) & 3], p.a11l[(t + 1) & 3], K1P_, NNIN_,
                p.a21h[t & 3], p.a21l[t & 3], K2P_, 0, 0);
        }
    } else if (blk < 1024) {               // B1(t=s-5)
        int t = s - 5;
        if (t >= 0 && t < T_) {
            int b2 = blk - 768;
            gemm_lstm_tile(tid, b2 & 31, b2 >> 5, smem,
                p.a21h[t & 3], p.a21l[t & 3], K2P_, p.w21, K2P_ / 32,
                p.bih1 + 2048, p.bhh1 + 2048, p.c11,
                p.a21h[(t + 1) & 3], p.a21l[(t + 1) & 3], K2P_, H_,
                p.yh[t & 3], p.yl[t & 3], KOP_, 0, 1);
        }
    } else if (blk < 1152) {               // M0(t=s-3)
        int t = s - 3;
        if (t >= 0 && t < T_) {
            mem_group(blk - 1024, tid, smem, p.S0[t & 1],
                p.mem0, p.link0, p.prec0, p.rw0, p.ww0, p.us0,
                p.a11h[t & 3], p.a11l[t & 3], K1P_);
        }
    } else if (blk < 1280) {               // M1(t=s-7)
        int t = s - 7;
        if (t >= 0 && t < T_) {
            mem_group(blk - 1152, tid, smem, p.S1[t & 1],
                p.mem1, p.link1, p.prec1, p.rw1, p.ww1, p.us1,
                p.yh[t & 3], p.yl[t & 3], KOP_);
        }
    } else if (blk < 1536) {               // Y(t=s-8)
        int t = s - 8;
        if (t >= 0 && t < T_) {
            int tile = blk - 1280;
            gemm_plain_tile(tid, tile & 31, tile >> 5, smem,
                p.yh[t & 3], p.yl[t & 3], KOP_, p.wo, KOP_, KOP_ / 32,
                p.bout, p.out + (size_t)t * IN_, T_ * IN_);
        }
    } else if (blk < 1624) {               // IF0(t=s-2)
        int t = s - 2;
        if (t >= 0 && t < T_) {
            int b2 = blk - 1536;
            gemm_iface_tile(tid, b2 % 11, b2 / 11, smem,
                p.a11h[t & 3], p.a11l[t & 3], K1P_,
                p.wif0h, p.wif0l, p.bif0, p.S0[t & 1]);
        }
    } else if (blk < 1712) {               // IF1(t=s-6)
        int t = s - 6;
        if (t >= 0 && t < T_) {
            int b2 = blk - 1624;
            gemm_iface_tile(tid, b2 % 11, b2 / 11, smem,
                p.yh[t & 3], p.yl[t & 3], KOP_,
                p.wif1h, p.wif1l, p.bif1, p.S1[t & 1]);
        }
    } else {                               // x(s+1) convert
        int tn = s + 1;
        if (tn < T_) {
            for (int i = (blk - 1712) * 256 + tid; i < B_ * IN_; i += 32 * 256) {
                int b = i >> 9, j = i & 511;
                float v = p.x[((size_t)b * T_ + tn) * IN_ + j];
                split2(v, &p.a10h[tn & 3][(size_t)b * K1P_ + j],
                          &p.a10l[tn & 3][(size_t)b * K1P_ + j]);
            }
        }
    }
}

// ---------------------------------------------------------------------------
// Setup kernels
// ---------------------------------------------------------------------------
__global__ __launch_bounds__(256) void conv_hi(
    const float* __restrict__ s1, int K1, const float* __restrict__ s2, int K2,
    int Nsrc, __bf16* __restrict__ hi, int Kd)
{
    int k = blockIdx.x * 256 + threadIdx.x;
    int n = blockIdx.y;
    if (k >= Kd) return;
    float v = 0.f;
    if (n < Nsrc) {
        if (k < K1) v = s1[(size_t)n * K1 + k];
        else if (k < K1 + K2) v = s2[(size_t)n * K2 + (k - K1)];
    }
    hi[(size_t)n * Kd + k] = (__bf16)v;
}

__global__ __launch_bounds__(256) void conv_hl(
    const float* __restrict__ src, int Nsrc, int K,
    __bf16* __restrict__ hi, __bf16* __restrict__ lo)
{
    int k = blockIdx.x * 256 + threadIdx.x;
    int n = blockIdx.y;
    if (k >= K) return;
    float v = (n < Nsrc) ? src[(size_t)n * K + k] : 0.f;
    split2(v, &hi[(size_t)n * K + k], &lo[(size_t)n * K + k]);
}

__global__ __launch_bounds__(256) void build_inp(const float* __restrict__ x,
                                                 __bf16* __restrict__ a1h,
                                                 __bf16* __restrict__ a1l)
{
    int idx = blockIdx.x * 256 + threadIdx.x;
    if (idx >= B_ * IN_) return;
    int b = idx >> 9, j = idx & 511;
    float v = x[(size_t)b * T_ * IN_ + j];
    split2(v, &a1h[b * K1P_ + j], &a1l[b * K1P_ + j]);
}

// ---------------------------------------------------------------------------
extern "C" void kernel_launch(void* const* d_in, const int* in_sizes, int n_in,
                              void* d_out, int out_size, void* d_ws, size_t ws_size,
                              hipStream_t stream)
{
    const float* x       = (const float*)d_in[0];
    const float* W_ih0   = (const float*)d_in[1];
    const float* W_hh0   = (const float*)d_in[2];
    const float* b_ih0   = (const float*)d_in[3];
    const float* b_hh0   = (const float*)d_in[4];
    const float* W_ih1   = (const float*)d_in[5];
    const float* W_hh1   = (const float*)d_in[6];
    const float* b_ih1   = (const float*)d_in[7];
    const float* b_hh1   = (const float*)d_in[8];
    const float* W_iface = (const float*)d_in[9];
    const float* b_iface = (const float*)d_in[10];
    const float* W_out   = (const float*)d_in[11];
    const float* b_out   = (const float*)d_in[12];

    P p;
    p.x = x;
    p.bih0 = b_ih0; p.bhh0 = b_hh0; p.bih1 = b_ih1; p.bhh1 = b_hh1;
    p.bif0 = b_iface; p.bif1 = b_iface + IFACE_;
    p.bout = b_out;
    p.out = (float*)d_out;

    char* ptr = (char*)d_ws;
    auto alloc = [&](size_t bytes) { char* r = ptr; ptr += (bytes + 255) & ~(size_t)255; return r; };

    // ---- zero zone (memset each call) ----
    char* zstart = ptr;
    for (int q = 0; q < 4; ++q) { p.a10h[q] = (__bf16*)alloc(B_ * K1P_ * 2); p.a10l[q] = (__bf16*)alloc(B_ * K1P_ * 2); }
    for (int q = 0; q < 4; ++q) { p.a11h[q] = (__bf16*)alloc(B_ * K1P_ * 2); p.a11l[q] = (__bf16*)alloc(B_ * K1P_ * 2); }
    for (int q = 0; q < 4; ++q) { p.a20h[q] = (__bf16*)alloc(B_ * K2P_ * 2); p.a20l[q] = (__bf16*)alloc(B_ * K2P_ * 2); }
    for (int q = 0; q < 4; ++q) { p.a21h[q] = (__bf16*)alloc(B_ * K2P_ * 2); p.a21l[q] = (__bf16*)alloc(B_ * K2P_ * 2); }
    for (int q = 0; q < 4; ++q) { p.yh[q]  = (__bf16*)alloc(B_ * KOP_ * 2);  p.yl[q]  = (__bf16*)alloc(B_ * KOP_ * 2); }
    p.c00 = (float*)alloc((size_t)B_ * H_ * 4);
    p.c01 = (float*)alloc((size_t)B_ * H_ * 4);
    p.c10 = (float*)alloc((size_t)B_ * H_ * 4);
    p.c11 = (float*)alloc((size_t)B_ * H_ * 4);
    p.mem0  = (float*)alloc((size_t)B_ * M_ * WC_ * 4);
    p.link0 = (float*)alloc((size_t)B_ * M_ * M_ * 4);
    p.prec0 = (float*)alloc((size_t)B_ * M_ * 4);
    p.rw0   = (float*)alloc((size_t)B_ * R_ * M_ * 4);
    p.ww0   = (float*)alloc((size_t)B_ * M_ * 4);
    p.us0   = (float*)alloc((size_t)B_ * M_ * 4);
    p.mem1  = (float*)alloc((size_t)B_ * M_ * WC_ * 4);
    p.link1 = (float*)alloc((size_t)B_ * M_ * M_ * 4);
    p.prec1 = (float*)alloc((size_t)B_ * M_ * 4);
    p.rw1   = (float*)alloc((size_t)B_ * R_ * M_ * 4);
    p.ww1   = (float*)alloc((size_t)B_ * M_ * 4);
    p.us1   = (float*)alloc((size_t)B_ * M_ * 4);
    size_t zbytes = (size_t)(ptr - zstart);

    // ---- weights (rewritten every call) ----
    p.w10 = (__bf16*)alloc(2048ull * K1P_ * 2);
    p.w11 = (__bf16*)alloc(2048ull * K1P_ * 2);
    p.w20 = (__bf16*)alloc(2048ull * K2P_ * 2);
    p.w21 = (__bf16*)alloc(2048ull * K2P_ * 2);
    p.wo  = (__bf16*)alloc(512ull * KOP_ * 2);
    p.wif0h = (__bf16*)alloc((size_t)IFP_ * 512 * 2);
    p.wif0l = (__bf16*)alloc((size_t)IFP_ * 512 * 2);
    p.wif1h = (__bf16*)alloc((size_t)IFP_ * 512 * 2);
    p.wif1l = (__bf16*)alloc((size_t)IFP_ * 512 * 2);
    // ---- iface activation buffers (written before read each slot) ----
    for (int q = 0; q < 2; ++q) p.S0[q] = (float*)alloc((size_t)B_ * IFP_ * 4);
    for (int q = 0; q < 2; ++q) p.S1[q] = (float*)alloc((size_t)B_ * IFP_ * 4);

    hipMemsetAsync(zstart, 0, zbytes, stream);

    conv_hi<<<dim3((K1P_ + 255) / 256, 2048), 256, 0, stream>>>(
        W_ih0, NNIN_, W_hh0, H_, 2048, p.w10, K1P_);
    conv_hi<<<dim3((K1P_ + 255) / 256, 2048), 256, 0, stream>>>(
        W_ih0 + 2048ull * NNIN_, NNIN_, W_hh0 + 2048ull * H_, H_, 2048, p.w11, K1P_);
    conv_hi<<<dim3((K2P_ + 255) / 256, 2048), 256, 0, stream>>>(
        W_ih1, H_, W_hh1, H_, 2048, p.w20, K2P_);
    conv_hi<<<dim3((K2P_ + 255) / 256, 2048), 256, 0, stream>>>(
        W_ih1 + 2048ull * H_, H_, W_hh1 + 2048ull * H_, H_, 2048, p.w21, K2P_);
    conv_hi<<<dim3((KOP_ + 255) / 256, 512), 256, 0, stream>>>(
        W_out, NNIN_, nullptr, 0, 512, p.wo, KOP_);
    conv_hl<<<dim3(2, IFP_), 256, 0, stream>>>(
        W_iface, IFACE_, 512, p.wif0h, p.wif0l);
    conv_hl<<<dim3(2, IFP_), 256, 0, stream>>>(
        W_iface + (size_t)IFACE_ * 512, IFACE_, 512, p.wif1h, p.wif1l);
    build_inp<<<(B_ * IN_ + 255) / 256, 256, 0, stream>>>(x, p.a10h[0], p.a10l[0]);

    // 40 pipeline slots cover t=0..31 for all 9 stages
    for (int s = 0; s < T_ + 8; ++s) {
        slot_kernel<<<1744, 256, 0, stream>>>(p, s);
    }
}